// Round 2
// baseline (3418.740 us; speedup 1.0000x reference)
//
#include <hip/hip_runtime.h>
#include <math.h>

#define DIMC 64
#define V25  25
#define NSTEP 3
#define BTOT 16384
#define LEAK 0.01f

typedef _Float16 half8  __attribute__((ext_vector_type(8)));
typedef _Float16 half4v __attribute__((ext_vector_type(4)));
typedef float    float4v __attribute__((ext_vector_type(4)));

#define MFMA16x16x32F16 __builtin_amdgcn_mfma_f32_16x16x32_f16

// LDS strides in _Float16 elements
#define CV_STRIDE 36   // cv view: [64][36]  (rows=c, cols=v)
#define VC_STRIDE 72   // vc view: [32][72]  (rows=v, cols=c)
#define W_STRIDE  72   // Wl: [64][72] per matrix

__device__ __forceinline__ int clampi03(int x) {
    return x < 0 ? 0 : (x > 3 ? 3 : x);
}

__launch_bounds__(256, 2)
__global__ void sode_kernel(const float* __restrict__ fp,     // first_point (B,64,25)
                            const float* __restrict__ ts,     // time_steps (4)
                            const float* __restrict__ Ag,     // A (25,25)
                            const float* __restrict__ W1g, const float* __restrict__ b1g,
                            const float* __restrict__ W2g, const float* __restrict__ b2g,
                            const float* __restrict__ Wpg, const float* __restrict__ bpg,
                            const float* __restrict__ peg,    // (67,64)
                            float* __restrict__ out)          // (4,B,64,25)
{
    __shared__ __align__(16) _Float16 Wl[3*64*W_STRIDE];   // 27648 B
    __shared__ __align__(16) _Float16 stg[4*2304];         // 18432 B — unified cv/vc staging, 1 buf/wave
    __shared__ __align__(16) float    pel[4*256];          //  4096 B — 4 pe rows per wave
    __shared__ __align__(16) float    bl[192];             //   768 B — b1|b2|bp

    const int tid  = threadIdx.x;
    const int lane = tid & 63;
    const int wid  = tid >> 6;
    const int m    = lane & 15;   // MFMA row/col within 16-tile
    const int q    = lane >> 4;   // quad (k-group / C-row group)
    const int n    = blockIdx.x * 4 + wid;   // sample id
    const int tmod = n & 63;                 // n % T

    // ---- cooperative fp16 W copy into LDS ([o][c], rows padded to 72) ----
    for (int idx = tid; idx < 64*64; idx += 256) {
        int o = idx >> 6, c = idx & 63;
        int d = o*W_STRIDE + c;
        Wl[d]                 = (_Float16)W1g[idx];
        Wl[64*W_STRIDE + d]   = (_Float16)W2g[idx];
        Wl[2*64*W_STRIDE + d] = (_Float16)Wpg[idx];
    }
    // ---- biases into LDS (block-shared) ----
    for (int i = tid; i < 192; i += 256) {
        int w = i >> 6, c = i & 63;
        bl[i] = (w == 0) ? b1g[c] : (w == 1) ? b2g[c] : bpg[c];
    }
    // ---- per-wave PE rows tmod..tmod+3 into LDS (wave-private) ----
    float* pew = pel + wid * 256;
    for (int i = lane; i < 256; i += 64)
        pew[i] = peg[(tmod + (i >> 6)) * 64 + (i & 63)];

    // ---- out[0] = first_point: fully-coalesced linear copy (4 samples/block contiguous) ----
    {
        const float4v* src = (const float4v*)(fp + (size_t)blockIdx.x * 6400);
        float4v*       dst = (float4v*)(out + (size_t)blockIdx.x * 6400);
        for (int i = tid; i < 1600; i += 256) dst[i] = src[i];
    }

    __syncthreads();   // only barrier — Wl/bl ready; everything after is wave-private

    _Float16* bcv = stg + wid * 2304;   // cv view [64][36]
    _Float16* bvc = stg + wid * 2304;   // vc view [32][72] — same memory (phases read-then-write)

    // ---- preload A^T B-fragments (B[k=u][n=v] = A[v][u]), zero pads kill u,v>=25 ----
    half8 BA[2];
    for (int nt = 0; nt < 2; ++nt) {
        int v = 16*nt + m;
        for (int j = 0; j < 8; ++j) {
            int u = 8*q + j;
            BA[nt][j] = (v < V25 && u < V25) ? (_Float16)Ag[v*V25 + u] : (_Float16)0.f;
        }
    }

    // ---- load Y in C-layout: element(row c = 16mt+4q+r, col v = 16nt+m) ----
    float4v Y[4][2], Acc[4][2], D[4][2], kreg[4][2];
    for (int mt = 0; mt < 4; ++mt)
      for (int nt = 0; nt < 2; ++nt) {
        float4v y;
        int v = 16*nt + m;
        for (int r = 0; r < 4; ++r) {
            int c = 16*mt + 4*q + r;
            y[r] = (v < V25) ? fp[(size_t)n*1600 + c*25 + v] : 0.f;
        }
        Y[mt][nt] = y;
      }

    const float4v z4 = {0.f, 0.f, 0.f, 0.f};

    // ---- stage x (+pe from LDS) into cv view ----
    auto stage = [&](int ti, auto&& fxn) {
        const float* perow = pew + ti * 64;
        for (int mt = 0; mt < 4; ++mt) {
            float4v pv = *(const float4v*)(perow + 16*mt + 4*q);
            for (int nt = 0; nt < 2; ++nt) {
                int v = 16*nt + m;
                for (int r = 0; r < 4; ++r)
                    bcv[(16*mt + 4*q + r)*CV_STRIDE + v] = (_Float16)(fxn(mt, nt, r) + pv[r]);
            }
        }
    };

    // ---- A-mix: cv -> vc (in place; all reads land in regs before writes) ----
    auto amix = [&]() {
        half8 af[4];
        for (int mt = 0; mt < 4; ++mt) {
            const half4v* p = (const half4v*)(bcv + (16*mt + m)*CV_STRIDE + 8*q);
            half4v lo = p[0], hi = p[1];
            half8 a;
            for (int j = 0; j < 4; ++j) { a[j] = lo[j]; a[4+j] = hi[j]; }
            af[mt] = a;
        }
        float4v acc[4][2];
        for (int mt = 0; mt < 4; ++mt)
          for (int nt = 0; nt < 2; ++nt)
            acc[mt][nt] = MFMA16x16x32F16(af[mt], BA[nt], z4, 0, 0, 0);
        for (int mt = 0; mt < 4; ++mt)
          for (int nt = 0; nt < 2; ++nt) {
            half4v h;
            for (int r = 0; r < 4; ++r) h[r] = (_Float16)acc[mt][nt][r];
            *(half4v*)(bvc + (16*nt + m)*VC_STRIDE + 16*mt + 4*q) = h;
          }
    };

    // ---- conv: vc (B-op) x Wl (A-op); bias from LDS; dst: 0=cv, 1=vc, 2=kreg ----
    auto conv = [&](const _Float16* Wbase, const float* bias, bool act, int dst) {
        half8 bf[2][2];
        for (int nt = 0; nt < 2; ++nt)
          for (int ks = 0; ks < 2; ++ks)
            bf[nt][ks] = *(const half8*)(bvc + (16*nt + m)*VC_STRIDE + 32*ks + 8*q);
        float4v acc[4][2];
        for (int mt = 0; mt < 4; ++mt) {
            const _Float16* wr = Wbase + (16*mt + m)*W_STRIDE + 8*q;
            half8 w0 = *(const half8*)(wr);
            half8 w1 = *(const half8*)(wr + 32);
            for (int nt = 0; nt < 2; ++nt) {
                float4v a = MFMA16x16x32F16(w0, bf[nt][0], z4, 0, 0, 0);
                acc[mt][nt] = MFMA16x16x32F16(w1, bf[nt][1], a, 0, 0, 0);
            }
        }
        for (int mt = 0; mt < 4; ++mt) {
            float4v bv = *(const float4v*)(bias + 16*mt + 4*q);
            for (int nt = 0; nt < 2; ++nt) {
                float4v a = acc[mt][nt];
                for (int r = 0; r < 4; ++r) {
                    float x = a[r] + bv[r];
                    if (act) x = (x >= 0.f) ? x : LEAK * x;
                    a[r] = x;
                }
                if (dst == 2) {
                    kreg[mt][nt] = a;
                } else if (dst == 1) {
                    half4v h;
                    for (int r = 0; r < 4; ++r) h[r] = (_Float16)a[r];
                    *(half4v*)(bvc + (16*nt + m)*VC_STRIDE + 16*mt + 4*q) = h;
                } else {
                    int v = 16*nt + m;
                    for (int r = 0; r < 4; ++r)
                        bcv[(16*mt + 4*q + r)*CV_STRIDE + v] = (_Float16)a[r];
                }
            }
        }
    };

    auto feval = [&]() {
        amix();                                            // x  -> vc
        conv(Wl,                 bl,       true,  0);      // vc -> cv
        amix();                                            // cv -> vc
        conv(Wl +   64*W_STRIDE, bl + 64,  true,  1);      // vc -> vc (in place)
        conv(Wl + 2*64*W_STRIDE, bl + 128, false, 2);      // vc -> kreg
    };

    // ---- coalesced store: Y -> LDS (linear sample layout, 2 half-passes) -> dwordx4 ----
    auto store_Y = [&](int step) {
        float* op = out + (size_t)step * BTOT * 1600 + (size_t)n * 1600;
        float* sf = (float*)bcv;   // staging buffer is dead here; 3200 B needed <= 4608 B
        for (int p = 0; p < 2; ++p) {
            for (int mt = 2*p; mt < 2*p + 2; ++mt)
              for (int nt = 0; nt < 2; ++nt) {
                int v = 16*nt + m;
                if (v < V25)
                  for (int r = 0; r < 4; ++r) {
                    int c = 16*mt + 4*q + r;
                    sf[(c - 32*p)*25 + v] = Y[mt][nt][r];
                  }
              }
            // same-wave DS ordering: reads below issue after writes above
            float4v* od = (float4v*)(op + p*800);
            const float4v* sv = (const float4v*)sf;
            for (int i = lane; i < 200; i += 64)
                od[i] = sv[i];
        }
    };

    float tsr[4];
    for (int i = 0; i < 4; ++i) tsr[i] = ts[i];

#pragma unroll 1
    for (int st = 0; st < NSTEP; ++st) {
        float t0 = tsr[st];
        float dt = tsr[st+1] - t0;
        float dt3 = dt * (1.f/3.f);
        int ti1 = clampi03((int)floorf(t0));
        int ti2 = clampi03((int)floorf(t0 + dt3));
        int ti3 = clampi03((int)floorf(t0 + 2.f*dt3));
        int ti4 = clampi03((int)floorf(t0 + dt));

        // eval 1: k1 = f(t0, Y)
        stage(ti1, [&](int mt, int nt, int r) { return Y[mt][nt][r]; });
        feval();
        for (int mt = 0; mt < 4; ++mt)
          for (int nt = 0; nt < 2; ++nt) { Acc[mt][nt] = kreg[mt][nt]; D[mt][nt] = kreg[mt][nt]; }
        // x2 = Y + dt/3 * k1
        stage(ti2, [&](int mt, int nt, int r) { return Y[mt][nt][r] + dt3 * kreg[mt][nt][r]; });

        // eval 2: k2
        feval();
        // x3 = Y + dt*k2 - dt/3*k1   (Acc currently == k1)
        stage(ti3, [&](int mt, int nt, int r) {
            return Y[mt][nt][r] + dt * kreg[mt][nt][r] - dt3 * Acc[mt][nt][r];
        });
        for (int mt = 0; mt < 4; ++mt)
          for (int nt = 0; nt < 2; ++nt)
            for (int r = 0; r < 4; ++r) {
                float kk = kreg[mt][nt][r];
                Acc[mt][nt][r] += 3.f * kk;   // k1 + 3k2
                D[mt][nt][r]   -= kk;         // k1 - k2
            }

        // eval 3: k3
        feval();
        // x4 = Y + dt*(k1 - k2 + k3)
        stage(ti4, [&](int mt, int nt, int r) {
            return Y[mt][nt][r] + dt * (D[mt][nt][r] + kreg[mt][nt][r]);
        });
        for (int mt = 0; mt < 4; ++mt)
          for (int nt = 0; nt < 2; ++nt)
            for (int r = 0; r < 4; ++r)
                Acc[mt][nt][r] += 3.f * kreg[mt][nt][r];   // k1 + 3k2 + 3k3

        // eval 4: k4 ; y1 = Y + dt*(Acc + k4)/8
        feval();
        for (int mt = 0; mt < 4; ++mt)
          for (int nt = 0; nt < 2; ++nt)
            for (int r = 0; r < 4; ++r)
                Y[mt][nt][r] += dt * 0.125f * (Acc[mt][nt][r] + kreg[mt][nt][r]);

        store_Y(st + 1);
    }
}

extern "C" void kernel_launch(void* const* d_in, const int* in_sizes, int n_in,
                              void* d_out, int out_size, void* d_ws, size_t ws_size,
                              hipStream_t stream) {
    const float* fp = (const float*)d_in[0];
    const float* ts = (const float*)d_in[1];
    const float* A  = (const float*)d_in[2];
    const float* W1 = (const float*)d_in[3];
    const float* b1 = (const float*)d_in[4];
    const float* W2 = (const float*)d_in[5];
    const float* b2 = (const float*)d_in[6];
    const float* Wp = (const float*)d_in[7];
    const float* bp = (const float*)d_in[8];
    const float* pe = (const float*)d_in[9];
    float* out = (float*)d_out;

    sode_kernel<<<dim3(BTOT/4), dim3(256), 0, stream>>>(fp, ts, A, W1, b1, W2, b2, Wp, bp, pe, out);
}

// Round 3
// 1547.901 us; speedup vs baseline: 2.2086x; 2.2086x over previous
//
#include <hip/hip_runtime.h>
#include <math.h>

#define DIMC 64
#define V25  25
#define NSTEP 3
#define BTOT 16384
#define LEAK 0.01f

typedef _Float16 half8  __attribute__((ext_vector_type(8)));
typedef _Float16 half4v __attribute__((ext_vector_type(4)));
typedef float    float4v __attribute__((ext_vector_type(4)));

#define MFMA16x16x32F16 __builtin_amdgcn_mfma_f32_16x16x32_f16

// LDS strides in _Float16 elements
#define CV_STRIDE 36   // buf_cv: [64][36]  (rows=c, cols=v)
#define VC_STRIDE 72   // buf_vc: [32][72]  (rows=v, cols=c)
#define W_STRIDE  72   // Wlds:   [64][72] per matrix

__device__ __forceinline__ int clampi03(int x) {
    return x < 0 ? 0 : (x > 3 ? 3 : x);
}

__launch_bounds__(256, 2)
__global__ void sode_kernel(const float* __restrict__ fp,     // first_point (B,64,25)
                            const float* __restrict__ ts,     // time_steps (4)
                            const float* __restrict__ Ag,     // A (25,25)
                            const float* __restrict__ W1g, const float* __restrict__ b1g,
                            const float* __restrict__ W2g, const float* __restrict__ b2g,
                            const float* __restrict__ Wpg, const float* __restrict__ bpg,
                            const float* __restrict__ peg,    // (67,64)
                            float* __restrict__ out)          // (4,B,64,25)
{
    __shared__ __align__(16) _Float16 Wl[3*64*W_STRIDE];      // 27648 B
    __shared__ __align__(16) _Float16 bufcv[4*64*CV_STRIDE];  // 18432 B
    __shared__ __align__(16) _Float16 bufvc[4*32*VC_STRIDE];  // 18432 B

    const int tid  = threadIdx.x;
    const int lane = tid & 63;
    const int wid  = tid >> 6;
    const int m    = lane & 15;   // MFMA row/col within 16-tile
    const int q    = lane >> 4;   // quad (k-group / C-row group)
    const int n    = blockIdx.x * 4 + wid;   // sample id
    const int tmod = n & 63;                 // n % T

    // ---- cooperative fp16 W copy into LDS ([o][c], rows padded to 72) ----
    for (int idx = tid; idx < 64*64; idx += 256) {
        int o = idx >> 6, c = idx & 63;
        int d = o*W_STRIDE + c;
        Wl[d]                 = (_Float16)W1g[idx];
        Wl[64*W_STRIDE + d]   = (_Float16)W2g[idx];
        Wl[2*64*W_STRIDE + d] = (_Float16)Wpg[idx];
    }

    // ---- out[0] = first_point: fully-coalesced linear copy (no LDS; before barrier) ----
    {
        const float4v* src = (const float4v*)(fp + (size_t)blockIdx.x * 6400);
        float4v*       dst = (float4v*)(out + (size_t)blockIdx.x * 6400);
        for (int i = tid; i < 1600; i += 256) dst[i] = src[i];
    }

    __syncthreads();   // only barrier in the kernel — everything after is wave-private

    _Float16* bcv = bufcv + wid * 64 * CV_STRIDE;
    _Float16* bvc = bufvc + wid * 32 * VC_STRIDE;

    // ---- preload A^T B-fragments (B[k=u][n=v] = A[v][u]), zero pads kill u,v>=25 ----
    half8 BA[2];
    for (int nt = 0; nt < 2; ++nt) {
        int v = 16*nt + m;
        for (int j = 0; j < 8; ++j) {
            int u = 8*q + j;
            BA[nt][j] = (v < V25 && u < V25) ? (_Float16)Ag[v*V25 + u] : (_Float16)0.f;
        }
    }

    // ---- load Y in C-layout: element(row c = 16mt+4q+r, col v = 16nt+m) ----
    float4v Y[4][2], Acc[4][2], D[4][2], kreg[4][2];
    for (int mt = 0; mt < 4; ++mt)
      for (int nt = 0; nt < 2; ++nt) {
        float4v y;
        int v = 16*nt + m;
        for (int r = 0; r < 4; ++r) {
            int c = 16*mt + 4*q + r;
            y[r] = (v < V25) ? fp[(size_t)n*1600 + c*25 + v] : 0.f;
        }
        Y[mt][nt] = y;
      }

    const float4v z4 = {0.f, 0.f, 0.f, 0.f};

    // ---- stage x (+pe) into buf_cv [c][v] fp16 ----
    auto stage = [&](int ti, auto&& fxn) {
        const float* perow = peg + (ti + tmod) * 64;
        for (int mt = 0; mt < 4; ++mt) {
            float pv[4];
            for (int r = 0; r < 4; ++r) pv[r] = perow[16*mt + 4*q + r];
            for (int nt = 0; nt < 2; ++nt) {
                int v = 16*nt + m;
                for (int r = 0; r < 4; ++r)
                    bcv[(16*mt + 4*q + r)*CV_STRIDE + v] = (_Float16)(fxn(mt, nt, r) + pv[r]);
            }
        }
    };

    // ---- A-mix: buf_cv -> buf_vc (transposed write) ----
    auto amix = [&]() {
        half8 af[4];
        for (int mt = 0; mt < 4; ++mt) {
            const half4v* p = (const half4v*)(bcv + (16*mt + m)*CV_STRIDE + 8*q);
            half4v lo = p[0], hi = p[1];
            half8 a;
            for (int j = 0; j < 4; ++j) { a[j] = lo[j]; a[4+j] = hi[j]; }
            af[mt] = a;
        }
        float4v acc[4][2];
        for (int mt = 0; mt < 4; ++mt)
          for (int nt = 0; nt < 2; ++nt)
            acc[mt][nt] = MFMA16x16x32F16(af[mt], BA[nt], z4, 0, 0, 0);
        for (int mt = 0; mt < 4; ++mt)
          for (int nt = 0; nt < 2; ++nt) {
            half4v h;
            for (int r = 0; r < 4; ++r) h[r] = (_Float16)acc[mt][nt][r];
            *(half4v*)(bvc + (16*nt + m)*VC_STRIDE + 16*mt + 4*q) = h;
          }
    };

    // ---- conv: buf_vc (B-op) x Wlds (A-op) ; dst: 0=buf_cv [o][v], 1=buf_vc transposed, 2=kreg ----
    auto conv = [&](const _Float16* Wbase, const float* bias, bool act, int dst) {
        half8 bf[2][2];
        for (int nt = 0; nt < 2; ++nt)
          for (int ks = 0; ks < 2; ++ks)
            bf[nt][ks] = *(const half8*)(bvc + (16*nt + m)*VC_STRIDE + 32*ks + 8*q);
        float4v acc[4][2];
        for (int mt = 0; mt < 4; ++mt) {
            const _Float16* wr = Wbase + (16*mt + m)*W_STRIDE + 8*q;
            half8 w0 = *(const half8*)(wr);
            half8 w1 = *(const half8*)(wr + 32);
            for (int nt = 0; nt < 2; ++nt) {
                float4v a = MFMA16x16x32F16(w0, bf[nt][0], z4, 0, 0, 0);
                acc[mt][nt] = MFMA16x16x32F16(w1, bf[nt][1], a, 0, 0, 0);
            }
        }
        for (int mt = 0; mt < 4; ++mt) {
            float bv[4];
            for (int r = 0; r < 4; ++r) bv[r] = bias[16*mt + 4*q + r];
            for (int nt = 0; nt < 2; ++nt) {
                float4v a = acc[mt][nt];
                for (int r = 0; r < 4; ++r) {
                    float x = a[r] + bv[r];
                    if (act) x = (x >= 0.f) ? x : LEAK * x;
                    a[r] = x;
                }
                if (dst == 2) {
                    kreg[mt][nt] = a;
                } else if (dst == 1) {
                    half4v h;
                    for (int r = 0; r < 4; ++r) h[r] = (_Float16)a[r];
                    *(half4v*)(bvc + (16*nt + m)*VC_STRIDE + 16*mt + 4*q) = h;
                } else {
                    int v = 16*nt + m;
                    for (int r = 0; r < 4; ++r)
                        bcv[(16*mt + 4*q + r)*CV_STRIDE + v] = (_Float16)a[r];
                }
            }
        }
    };

    auto feval = [&]() {
        amix();                                            // x  -> t1 (buf_vc)
        conv(Wl,                 b1g, true,  0);           // t1 -> t2 (buf_cv)
        amix();                                            // t2 -> t3 (buf_vc)
        conv(Wl +   64*W_STRIDE, b2g, true,  1);           // t3 -> t4 (buf_vc, in place)
        conv(Wl + 2*64*W_STRIDE, bpg, false, 2);           // t4 -> k  (regs)
    };

    // ---- coalesced store: Y -> LDS (linear sample layout, 2 half-passes) -> dwordx4 ----
    // Reuses buf_cv (dead at store time; 3200 B needed <= 4608 B). Aliasing is only
    // touched here, outside the feval phase chain, so loop codegen is unaffected.
    auto store_Y = [&](int step) {
        float* op = out + (size_t)step * BTOT * 1600 + (size_t)n * 1600;
        float* sf = (float*)bcv;
        for (int p = 0; p < 2; ++p) {
            for (int mt = 2*p; mt < 2*p + 2; ++mt)
              for (int nt = 0; nt < 2; ++nt) {
                int v = 16*nt + m;
                if (v < V25)
                  for (int r = 0; r < 4; ++r)
                    sf[(16*(mt - 2*p) + 4*q + r)*25 + v] = Y[mt][nt][r];
              }
            // compiler orders the reads below after the writes above (same object)
            float4v* od = (float4v*)(op + p*800);
            const float4v* sv = (const float4v*)sf;
            for (int i = lane; i < 200; i += 64)
                od[i] = sv[i];
        }
    };

    float tsr[4];
    for (int i = 0; i < 4; ++i) tsr[i] = ts[i];

#pragma unroll 1
    for (int st = 0; st < NSTEP; ++st) {
        float t0 = tsr[st];
        float dt = tsr[st+1] - t0;
        float dt3 = dt * (1.f/3.f);
        int ti1 = clampi03((int)floorf(t0));
        int ti2 = clampi03((int)floorf(t0 + dt3));
        int ti3 = clampi03((int)floorf(t0 + 2.f*dt3));
        int ti4 = clampi03((int)floorf(t0 + dt));

        // eval 1: k1 = f(t0, Y)
        stage(ti1, [&](int mt, int nt, int r) { return Y[mt][nt][r]; });
        feval();
        for (int mt = 0; mt < 4; ++mt)
          for (int nt = 0; nt < 2; ++nt) { Acc[mt][nt] = kreg[mt][nt]; D[mt][nt] = kreg[mt][nt]; }
        // x2 = Y + dt/3 * k1
        stage(ti2, [&](int mt, int nt, int r) { return Y[mt][nt][r] + dt3 * kreg[mt][nt][r]; });

        // eval 2: k2
        feval();
        // x3 = Y + dt*k2 - dt/3*k1   (Acc currently == k1)
        stage(ti3, [&](int mt, int nt, int r) {
            return Y[mt][nt][r] + dt * kreg[mt][nt][r] - dt3 * Acc[mt][nt][r];
        });
        for (int mt = 0; mt < 4; ++mt)
          for (int nt = 0; nt < 2; ++nt)
            for (int r = 0; r < 4; ++r) {
                float kk = kreg[mt][nt][r];
                Acc[mt][nt][r] += 3.f * kk;   // k1 + 3k2
                D[mt][nt][r]   -= kk;         // k1 - k2
            }

        // eval 3: k3
        feval();
        // x4 = Y + dt*(k1 - k2 + k3)
        stage(ti4, [&](int mt, int nt, int r) {
            return Y[mt][nt][r] + dt * (D[mt][nt][r] + kreg[mt][nt][r]);
        });
        for (int mt = 0; mt < 4; ++mt)
          for (int nt = 0; nt < 2; ++nt)
            for (int r = 0; r < 4; ++r)
                Acc[mt][nt][r] += 3.f * kreg[mt][nt][r];   // k1 + 3k2 + 3k3

        // eval 4: k4 ; y1 = Y + dt*(Acc + k4)/8
        feval();
        for (int mt = 0; mt < 4; ++mt)
          for (int nt = 0; nt < 2; ++nt)
            for (int r = 0; r < 4; ++r)
                Y[mt][nt][r] += dt * 0.125f * (Acc[mt][nt][r] + kreg[mt][nt][r]);

        store_Y(st + 1);
    }
}

extern "C" void kernel_launch(void* const* d_in, const int* in_sizes, int n_in,
                              void* d_out, int out_size, void* d_ws, size_t ws_size,
                              hipStream_t stream) {
    const float* fp = (const float*)d_in[0];
    const float* ts = (const float*)d_in[1];
    const float* A  = (const float*)d_in[2];
    const float* W1 = (const float*)d_in[3];
    const float* b1 = (const float*)d_in[4];
    const float* W2 = (const float*)d_in[5];
    const float* b2 = (const float*)d_in[6];
    const float* Wp = (const float*)d_in[7];
    const float* bp = (const float*)d_in[8];
    const float* pe = (const float*)d_in[9];
    float* out = (float*)d_out;

    sode_kernel<<<dim3(BTOT/4), dim3(256), 0, stream>>>(fp, ts, A, W1, b1, W2, b2, Wp, bp, pe, out);
}